// Round 5
// baseline (635.537 us; speedup 1.0000x reference)
//
#include <hip/hip_runtime.h>
#include <hip/hip_fp16.h>

#define TLEN 512
#define HDIM 32
#define FOUT 20
#define HST  36   // h row stride in halfwords; 72B rows + b64-pair reads -> 0 bank conflicts (measured R3)

typedef __attribute__((ext_vector_type(8))) short bf16x8;
typedef __attribute__((ext_vector_type(4))) short s16x4;
typedef __attribute__((ext_vector_type(4))) float f32x4;

__device__ __forceinline__ float sigm(float v) {
  float e = __builtin_amdgcn_exp2f(-1.4426950408889634f * v);
  return __builtin_amdgcn_rcpf(1.0f + e);
}
__device__ __forceinline__ float tanh_f(float v) {
  float e = __builtin_amdgcn_exp2f(2.8853900817779268f * v);
  return 1.0f - 2.0f * __builtin_amdgcn_rcpf(1.0f + e);
}
// round-to-nearest-even bf16 hi/lo split: v ~= hi + lo (~16-bit mantissa coverage)
__device__ __forceinline__ void hilo(float v, short& h, short& l) {
  unsigned u = __builtin_bit_cast(unsigned, v);
  unsigned r = u + 0x7fffu + ((u >> 16) & 1u);
  h = (short)(r >> 16);
  float hf = __builtin_bit_cast(float, r & 0xffff0000u);
  float res = v - hf;
  unsigned u2 = __builtin_bit_cast(unsigned, res);
  unsigned r2 = u2 + 0x7fffu + ((u2 >> 16) & 1u);
  l = (short)(r2 >> 16);
}
// Barrier draining only LDS (lgkmcnt) — global output stores keep flowing.
__device__ __forceinline__ void barrier_lgkm() {
  asm volatile("s_waitcnt lgkmcnt(0)\n\ts_barrier" ::: "memory");
}
// lane ^= 8 within each 16-lane row (row_ror:8). MUST be executed with all
// row lanes active (bound_ctrl:0 reads 0 from EXEC-disabled sources).
__device__ __forceinline__ float dpp_xor8(float x) {
  return __builtin_bit_cast(float,
      __builtin_amdgcn_mov_dpp(__builtin_bit_cast(int, x), 0x128, 0xF, 0xF, true));
}
// two 8B-aligned ds_read_b64 -> one bf16x8 fragment (conflict-free at HST=36)
__device__ __forceinline__ bf16x8 read_h(const short* buf, int off) {
  s16x4 a = *(const s16x4*)(buf + off);
  s16x4 b = *(const s16x4*)(buf + off + 4);
  bf16x8 r;
  r[0]=a[0]; r[1]=a[1]; r[2]=a[2]; r[3]=a[3];
  r[4]=b[0]; r[5]=b[1]; r[6]=b[2]; r[7]=b[3];
  return r;
}
// g[0..3] = i,f,g,o gates of ONE (batch,unit) position
__device__ __forceinline__ float lstm_update(const f32x4& g, float& c) {
  float iv = sigm(g[0]), fv = sigm(g[1]), gv = tanh_f(g[2]), ov = sigm(g[3]);
  c = fv * c + iv * gv;
  return ov * tanh_f(c);
}

// Grid 512 x 512thr: block = 8 waves, 8 batch rows -> 2 independent blocks/CU
// (4 waves/SIMD, decoupled barriers). MFMA: A = bf16 hi/lo weights (M = 16 gate
// rows, m -> unit 4w+(m>>2), gate m&3), B = bf16 hi/lo h (cols 0..7 = batch,
// 8..15 = zeros). C layout => lane (n,q) reg r = gate r of (batch n, unit 4w+q).
// Update lane-split: lanes n<8 do the L1 position, lanes n>=8 do the L2
// position of batch n-8 (gates pulled via DPP row_ror:8 with full EXEC).
// Pipelined: iteration t computes L1(t) and L2(t-1); ONE lgkm-barrier/step.
__global__ __launch_bounds__(512, 4) void lstm_seq_kernel(
    const float* __restrict__ xg,
    const float* __restrict__ Wih1, const float* __restrict__ Whh1,
    const float* __restrict__ bih1, const float* __restrict__ bhh1,
    const float* __restrict__ Wih2, const float* __restrict__ Whh2,
    const float* __restrict__ bih2, const float* __restrict__ bhh2,
    const float* __restrict__ Wout, const float* __restrict__ bout,
    float* __restrict__ out)
{
  __shared__ float xl[8 * 1028];            // x staged fp32 (exact), stride 1028
  // [which][par][16*HST]: which 0=h1hi 1=h1lo 2=h2hi 3=h2lo; rows 8-15 stay 0
  __shared__ short hb[4][2][16 * HST];

  const int tid  = threadIdx.x;
  const int w    = tid >> 6;
  const int lane = tid & 63;
  const int n    = lane & 15;
  const int q    = lane >> 4;
  const int q4   = q * 4;
  const int q8   = q * 8;
  const int b0   = blockIdx.x * 8;
  const int p    = w & 1;                   // out tile (rows 16p..16p+15)
  const int u    = 4 * w + q;               // this lane's update unit
  const bool upd1 = (n < 8);
  const int xr   = (n & 7) * 1028;

  // ---- stage x[b0..b0+7][0..1024) fp32, float4-coalesced
  for (int idx = tid; idx < 2048; idx += 512) {
    int row = idx >> 8, c4 = idx & 255;
    *(float4*)&xl[row * 1028 + 4 * c4] =
        *(const float4*)&xg[((size_t)(b0 + row) << 10) + 4 * c4];
  }
  // ---- zero h buffers (rows 8-15 must be zero forever; rows 0-7 = h(-1)=0)
  for (int idx = tid; idx < 4 * 2 * 16 * HST; idx += 512)
    (&hb[0][0][0])[idx] = 0;

  // ---- bf16 hi/lo weight A-fragments: A[m=n][k=q8+j]; m -> gate m&3, unit 4w+(m>>2)
  const int og = (n & 3) * HDIM + 4 * w + (n >> 2);
  bf16x8 Whh1h, Whh1l, Wih2h, Wih2l, Whh2h, Whh2l;
  #pragma unroll
  for (int j = 0; j < 8; j++) {
    short hh, ll;
    hilo(Whh1[og * HDIM + q8 + j], hh, ll); Whh1h[j] = hh; Whh1l[j] = ll;
    hilo(Wih2[og * HDIM + q8 + j], hh, ll); Wih2h[j] = hh; Wih2l[j] = ll;
    hilo(Whh2[og * HDIM + q8 + j], hh, ll); Whh2h[j] = hh; Whh2l[j] = ll;
  }
  float b1c[4], b2c[4], wxa[4], wxb[4], boc[4];
  #pragma unroll
  for (int r = 0; r < 4; r++) {
    int gr = r * HDIM + u;
    b1c[r] = bih1[gr] + bhh1[gr];
    b2c[r] = bih2[gr] + bhh2[gr];
    wxa[r] = Wih1[gr * 2 + 0];
    wxb[r] = Wih1[gr * 2 + 1];
    int orow = 16 * p + q4 + r;
    boc[r] = (orow < FOUT) ? bout[orow] : 0.0f;
  }
  bf16x8 WoH = {0,0,0,0,0,0,0,0}, WoL = {0,0,0,0,0,0,0,0};
  {
    int orow = 16 * p + n;
    if (orow < FOUT) {
      #pragma unroll
      for (int j = 0; j < 8; j++) {
        short hh, ll;
        hilo(Wout[orow * HDIM + q8 + j], hh, ll); WoH[j] = hh; WoL[j] = ll;
      }
    }
  }

  // lane-split write targets: n<8 -> h1 (batch n), n>=8 -> h2 (batch n-8)
  const int woff = (upd1 ? n : (n - 8)) * HST + u;
  short* whp[2] = { upd1 ? &hb[0][0][0] : &hb[2][0][0],
                    upd1 ? &hb[0][1][0] : &hb[2][1][0] };
  short* wlp[2] = { upd1 ? &hb[1][0][0] : &hb[3][0][0],
                    upd1 ? &hb[1][1][0] : &hb[3][1][0] };
  const int aoff = n * HST + q8;
  float c = 0.0f;                           // c1 in lanes n<8, c2 in lanes n>=8

  bf16x8 h1h = {0,0,0,0,0,0,0,0}, h1l = {0,0,0,0,0,0,0,0};
  bf16x8 h2h = {0,0,0,0,0,0,0,0}, h2l = {0,0,0,0,0,0,0,0};

  __syncthreads();   // staging + zeroing visible (full barrier once)

  // ======== head: t=0, L1 only (h1(-1)=0 -> pure VALU)
  {
    float2 xv = *(const float2*)&xl[xr];
    if (upd1) {
      f32x4 g;
      #pragma unroll
      for (int r = 0; r < 4; r++) g[r] = fmaf(xv.y, wxb[r], fmaf(xv.x, wxa[r], b1c[r]));
      float hn = lstm_update(g, c);
      short hh, ll; hilo(hn, hh, ll);
      hb[0][0][n * HST + u] = hh; hb[1][0][n * HST + u] = ll;
    }
    barrier_lgkm();
    h1h = read_h(&hb[0][0][0], aoff);       // h1(0); h2 frags stay 0 = h2(-1)
    h1l = read_h(&hb[1][0][0], aoff);
  }

  // ======== main: iteration t computes L1(t) and L2(t-1)
  for (int t = 1; t < TLEN; ++t) {
    const int par = t & 1;
    float2 xv = *(const float2*)&xl[xr + 2 * t];

    // L1(t): 3-product hi/lo, split into 2 chains (depth 2)
    f32x4 g1a, g1b = { 0.0f, 0.0f, 0.0f, 0.0f };
    #pragma unroll
    for (int r = 0; r < 4; r++) g1a[r] = fmaf(xv.y, wxb[r], fmaf(xv.x, wxa[r], b1c[r]));
    g1a = __builtin_amdgcn_mfma_f32_16x16x32_bf16(Whh1h, h1h, g1a, 0, 0, 0);
    g1b = __builtin_amdgcn_mfma_f32_16x16x32_bf16(Whh1l, h1h, g1b, 0, 0, 0);
    g1a = __builtin_amdgcn_mfma_f32_16x16x32_bf16(Whh1h, h1l, g1a, 0, 0, 0);

    // L2(t-1): 6 products in 3 chains of depth 2
    f32x4 ga = { b2c[0], b2c[1], b2c[2], b2c[3] };
    f32x4 gb = { 0.0f, 0.0f, 0.0f, 0.0f };
    f32x4 gc = { 0.0f, 0.0f, 0.0f, 0.0f };
    ga = __builtin_amdgcn_mfma_f32_16x16x32_bf16(Wih2h, h1h, ga, 0, 0, 0);
    gb = __builtin_amdgcn_mfma_f32_16x16x32_bf16(Whh2h, h2h, gb, 0, 0, 0);
    gc = __builtin_amdgcn_mfma_f32_16x16x32_bf16(Wih2l, h1h, gc, 0, 0, 0);
    ga = __builtin_amdgcn_mfma_f32_16x16x32_bf16(Wih2h, h1l, ga, 0, 0, 0);
    gb = __builtin_amdgcn_mfma_f32_16x16x32_bf16(Whh2h, h2l, gb, 0, 0, 0);
    gc = __builtin_amdgcn_mfma_f32_16x16x32_bf16(Whh2l, h2h, gc, 0, 0, 0);

    // lanes n>=8 pull the L2 gates of batch n-8 via DPP (full EXEC here)
    f32x4 g;
    #pragma unroll
    for (int r = 0; r < 4; r++) {
      float g1r = g1a[r] + g1b[r];
      float g2r = ga[r] + gb[r] + gc[r];
      float grr = dpp_xor8(g2r);
      g[r] = upd1 ? g1r : grr;
    }
    float hn = lstm_update(g, c);           // L1(t) in n<8, L2(t-1) in n>=8
    short hh, ll; hilo(hn, hh, ll);
    whp[par][woff] = hh; wlp[par][woff] = ll;

    barrier_lgkm();                         // h1(t), h2(t-1) visible

    h1h = read_h(&hb[0][par][0], aoff);
    h1l = read_h(&hb[1][par][0], aoff);
    h2h = read_h(&hb[2][par][0], aoff);
    h2l = read_h(&hb[3][par][0], aoff);

    // out(s=t-1) = Wout @ h2(s) + bout, rotated: wave pair (s&3)
    const int s = t - 1;
    if ((w >> 1) == (s & 3)) {
      f32x4 ao = { boc[0], boc[1], boc[2], boc[3] };
      ao = __builtin_amdgcn_mfma_f32_16x16x32_bf16(WoH, h2h, ao, 0, 0, 0);
      ao = __builtin_amdgcn_mfma_f32_16x16x32_bf16(WoL, h2h, ao, 0, 0, 0);
      ao = __builtin_amdgcn_mfma_f32_16x16x32_bf16(WoH, h2l, ao, 0, 0, 0);
      if ((p == 0 || q == 0) && n < 8) {
        float4 st = { ao[0], ao[1], ao[2], ao[3] };
        *(float4*)&out[((size_t)(b0 + n) * TLEN + s) * FOUT + 16 * p + q4] = st;
      }
    }
  }

  // ======== tail: L2(511) + out(511)
  {
    f32x4 ga = { b2c[0], b2c[1], b2c[2], b2c[3] };
    f32x4 gb = { 0.0f, 0.0f, 0.0f, 0.0f };
    f32x4 gc = { 0.0f, 0.0f, 0.0f, 0.0f };
    ga = __builtin_amdgcn_mfma_f32_16x16x32_bf16(Wih2h, h1h, ga, 0, 0, 0);
    gb = __builtin_amdgcn_mfma_f32_16x16x32_bf16(Whh2h, h2h, gb, 0, 0, 0);
    gc = __builtin_amdgcn_mfma_f32_16x16x32_bf16(Wih2l, h1h, gc, 0, 0, 0);
    ga = __builtin_amdgcn_mfma_f32_16x16x32_bf16(Wih2h, h1l, ga, 0, 0, 0);
    gb = __builtin_amdgcn_mfma_f32_16x16x32_bf16(Whh2h, h2l, gb, 0, 0, 0);
    gc = __builtin_amdgcn_mfma_f32_16x16x32_bf16(Whh2l, h2h, gc, 0, 0, 0);
    // DPP with full EXEC (R4 bug: doing this under !upd1 reads 0 from masked lanes)
    f32x4 g;
    #pragma unroll
    for (int r = 0; r < 4; r++) g[r] = dpp_xor8(ga[r] + gb[r] + gc[r]);
    if (!upd1) {
      float hn = lstm_update(g, c);
      short hh, ll; hilo(hn, hh, ll);
      hb[2][0][(n - 8) * HST + u] = hh; hb[3][0][(n - 8) * HST + u] = ll;
    }
    barrier_lgkm();
    h2h = read_h(&hb[2][0][0], aoff);       // h2(511)
    h2l = read_h(&hb[3][0][0], aoff);
    if ((w >> 1) == 3) {                    // s=511, 511&3==3
      f32x4 ao = { boc[0], boc[1], boc[2], boc[3] };
      ao = __builtin_amdgcn_mfma_f32_16x16x32_bf16(WoH, h2h, ao, 0, 0, 0);
      ao = __builtin_amdgcn_mfma_f32_16x16x32_bf16(WoL, h2h, ao, 0, 0, 0);
      ao = __builtin_amdgcn_mfma_f32_16x16x32_bf16(WoH, h2l, ao, 0, 0, 0);
      if ((p == 0 || q == 0) && n < 8) {
        float4 st = { ao[0], ao[1], ao[2], ao[3] };
        *(float4*)&out[((size_t)(b0 + n) * TLEN + 511) * FOUT + 16 * p + q4] = st;
      }
    }
  }
}

extern "C" void kernel_launch(void* const* d_in, const int* in_sizes, int n_in,
                              void* d_out, int out_size, void* d_ws, size_t ws_size,
                              hipStream_t stream) {
  const float* xg   = (const float*)d_in[0];
  const float* Wih1 = (const float*)d_in[1];
  const float* Whh1 = (const float*)d_in[2];
  const float* bih1 = (const float*)d_in[3];
  const float* bhh1 = (const float*)d_in[4];
  const float* Wih2 = (const float*)d_in[5];
  const float* Whh2 = (const float*)d_in[6];
  const float* bih2 = (const float*)d_in[7];
  const float* bhh2 = (const float*)d_in[8];
  const float* Wout = (const float*)d_in[9];
  const float* bout = (const float*)d_in[10];
  float* out = (float*)d_out;

  hipLaunchKernelGGL(lstm_seq_kernel, dim3(512), dim3(512), 0, stream,
                     xg, Wih1, Whh1, bih1, bhh1, Wih2, Whh2, bih2, bhh2, Wout, bout, out);
}